// Round 5
// baseline (1609.935 us; speedup 1.0000x reference)
//
#include <hip/hip_runtime.h>
#include <math.h>

#define FEAT 128
#define BSHIFT 5            // 32 nodes per bucket
#define BNODES 32
#define TSTRIDE 33          // padded node-stride of transposed LDS tile

__device__ __forceinline__ float edge_weight(float d, float scale, float fw, float fb) {
    // scale already includes +1e-6
    float t = fmaxf(d / scale, 0.0f);
    float decay = expf(-t * t);
    float g = 1.0f / (1.0f + expf(-(d * fw + fb)));
    float w = decay * g;
    if (!isfinite(w)) w = 0.0f;
    return w;
}

__device__ __forceinline__ unsigned int bf16_rne(float f) {
    unsigned int b = __float_as_uint(f);
    return (b + 0x7FFFu + ((b >> 16) & 1u)) >> 16;
}

// ---------------- x -> bf16 table ----------------
__global__ __launch_bounds__(256) void convert_kernel(const float4* __restrict__ x4,
                                                      uint2* __restrict__ xbf,
                                                      int n4) {
    int i = blockIdx.x * 256 + threadIdx.x;
    if (i >= n4) return;
    float4 v = x4[i];
    uint2 o;
    o.x = (bf16_rne(v.y) << 16) | bf16_rne(v.x);
    o.y = (bf16_rne(v.w) << 16) | bf16_rne(v.z);
    xbf[i] = o;
}

// ---------------- CSR offsets (for degree + bucket bases) ----------------
__global__ __launch_bounds__(256) void hist_kernel(const int* __restrict__ recv,
                                                   int* __restrict__ off, int E) {
    int e = blockIdx.x * 256 + threadIdx.x;
    if (e < E) atomicAdd(&off[recv[e] + 1], 1);
}

__global__ __launch_bounds__(1024) void scan_kernel(int* __restrict__ off, int N) {
    __shared__ int part[1024];
    int t = threadIdx.x;
    int chunk = (N + 1023) >> 10;
    int lo = t * chunk, hi = min(lo + chunk, N);
    int s = 0;
    for (int i = lo; i < hi; ++i) s += off[1 + i];
    part[t] = s;
    __syncthreads();
    for (int d = 1; d < 1024; d <<= 1) {
        int v = (t >= d) ? part[t - d] : 0;
        __syncthreads();
        part[t] += v;
        __syncthreads();
    }
    int run = part[t] - s;
    for (int i = lo; i < hi; ++i) {
        run += off[1 + i];
        off[1 + i] = run;   // inclusive -> CSR offset for node i+1
    }
    if (t == 0) off[0] = 0;
}

__global__ __launch_bounds__(256) void bcur_init_kernel(const int* __restrict__ off,
                                                        int* __restrict__ bcur,
                                                        int nbuck) {
    int b = blockIdx.x * 256 + threadIdx.x;
    if (b < nbuck) bcur[b] = off[b << BSHIFT];
}

// ---------------- bucket scatter: 8B record {w | local<<16 | sender} --------
__global__ __launch_bounds__(256) void bucket_scatter_kernel(
    const int* __restrict__ sender, const int* __restrict__ recv,
    const float* __restrict__ edge_len,
    const float* __restrict__ log_scale, const float* __restrict__ filter_w,
    const float* __restrict__ filter_b,
    int* __restrict__ bcur, unsigned long long* __restrict__ buf, int E) {
    int e = blockIdx.x * 256 + threadIdx.x;
    if (e >= E) return;
    float scale = expf(log_scale[0]) + 1e-6f;
    float w = edge_weight(edge_len[e], scale, filter_w[0], filter_b[0]);
    int r = recv[e];
    int s = sender[e];
    int pos = atomicAdd(&bcur[r >> BSHIFT], 1);
    unsigned long long rec = ((unsigned long long)__float_as_uint(w) << 32)
                           | (unsigned int)(s & 0xFFFF)
                           | ((unsigned int)(r & (BNODES - 1)) << 16);
    buf[pos] = rec;
}

// ---------------- bucket aggregate: LDS ds_add_f32, transposed tile ---------
// One block per bucket (32 nodes). 16 lanes per record, lane owns 8 feats
// (one uint4 of the bf16 row). aggT[feat][node] with node-stride 33 so the
// 16-lane 8-float spans land ~4-way in banks instead of 16-way.
__global__ __launch_bounds__(256) void bucket_aggregate_kernel(
    const uint4* __restrict__ xbf4, const unsigned long long* __restrict__ buf,
    const int* __restrict__ off, uint4* __restrict__ agg_bf4, int N) {
    __shared__ float aggT[FEAT * TSTRIDE];  // 16.5 KB
    int n0 = blockIdx.x << BSHIFT;
    int nEnd = min(n0 + BNODES, N);
    for (int i = threadIdx.x; i < FEAT * TSTRIDE; i += 256) aggT[i] = 0.f;
    __syncthreads();

    int lo = off[n0], hi = off[nEnd];
    int lane = threadIdx.x & 15;
    int grp  = threadIdx.x >> 4;    // 16 record-groups
    int fbase = lane * 8;

    int i = lo + grp;
    for (; i + 16 < hi; i += 32) {
        unsigned long long ra = buf[i];
        unsigned long long rb = buf[i + 16];
        unsigned int la = (unsigned int)ra, lb = (unsigned int)rb;
        float wa = __uint_as_float((unsigned int)(ra >> 32));
        float wb = __uint_as_float((unsigned int)(rb >> 32));
        int sa = la & 0xFFFF, sb = lb & 0xFFFF;
        int na = (la >> 16) & (BNODES - 1), nb = (lb >> 16) & (BNODES - 1);
        uint4 ua = xbf4[(size_t)sa * 16 + lane];
        uint4 ub = xbf4[(size_t)sb * 16 + lane];
        float fa[8], fb[8];
        fa[0] = __uint_as_float(ua.x << 16); fa[1] = __uint_as_float(ua.x & 0xFFFF0000u);
        fa[2] = __uint_as_float(ua.y << 16); fa[3] = __uint_as_float(ua.y & 0xFFFF0000u);
        fa[4] = __uint_as_float(ua.z << 16); fa[5] = __uint_as_float(ua.z & 0xFFFF0000u);
        fa[6] = __uint_as_float(ua.w << 16); fa[7] = __uint_as_float(ua.w & 0xFFFF0000u);
        fb[0] = __uint_as_float(ub.x << 16); fb[1] = __uint_as_float(ub.x & 0xFFFF0000u);
        fb[2] = __uint_as_float(ub.y << 16); fb[3] = __uint_as_float(ub.y & 0xFFFF0000u);
        fb[4] = __uint_as_float(ub.z << 16); fb[5] = __uint_as_float(ub.z & 0xFFFF0000u);
        fb[6] = __uint_as_float(ub.w << 16); fb[7] = __uint_as_float(ub.w & 0xFFFF0000u);
#pragma unroll
        for (int j = 0; j < 8; ++j)
            atomicAdd(&aggT[(fbase + j) * TSTRIDE + na], wa * fa[j]);
#pragma unroll
        for (int j = 0; j < 8; ++j)
            atomicAdd(&aggT[(fbase + j) * TSTRIDE + nb], wb * fb[j]);
    }
    if (i < hi) {
        unsigned long long ra = buf[i];
        unsigned int la = (unsigned int)ra;
        float wa = __uint_as_float((unsigned int)(ra >> 32));
        int sa = la & 0xFFFF;
        int na = (la >> 16) & (BNODES - 1);
        uint4 ua = xbf4[(size_t)sa * 16 + lane];
        float fa[8];
        fa[0] = __uint_as_float(ua.x << 16); fa[1] = __uint_as_float(ua.x & 0xFFFF0000u);
        fa[2] = __uint_as_float(ua.y << 16); fa[3] = __uint_as_float(ua.y & 0xFFFF0000u);
        fa[4] = __uint_as_float(ua.z << 16); fa[5] = __uint_as_float(ua.z & 0xFFFF0000u);
        fa[6] = __uint_as_float(ua.w << 16); fa[7] = __uint_as_float(ua.w & 0xFFFF0000u);
#pragma unroll
        for (int j = 0; j < 8; ++j)
            atomicAdd(&aggT[(fbase + j) * TSTRIDE + na], wa * fa[j]);
    }
    __syncthreads();

    // writeout: bf16-pack rows from transposed tile
    for (int t = threadIdx.x; t < BNODES * 16; t += 256) {
        int local = t >> 4;
        int q = t & 15;
        int n = n0 + local;
        if (n < nEnd) {
            float v[8];
#pragma unroll
            for (int j = 0; j < 8; ++j) v[j] = aggT[(q * 8 + j) * TSTRIDE + local];
            uint4 o;
            o.x = (bf16_rne(v[1]) << 16) | bf16_rne(v[0]);
            o.y = (bf16_rne(v[3]) << 16) | bf16_rne(v[2]);
            o.z = (bf16_rne(v[5]) << 16) | bf16_rne(v[4]);
            o.w = (bf16_rne(v[7]) << 16) | bf16_rne(v[6]);
            agg_bf4[(size_t)n * 16 + q] = o;
        }
    }
}

// ---------------- finalize: tiled GEMM, out = x + (agg/deg) @ W --------------
__global__ __launch_bounds__(256) void finalize_kernel(
    const float* __restrict__ x, const uint4* __restrict__ agg_bf4,
    const int* __restrict__ off, const float* __restrict__ Wm,
    float* __restrict__ out, int N) {
    __shared__ float aggS[64 * 128];  // 32 KB
    __shared__ float Ws[128 * 64];    // 32 KB
    const int n0 = blockIdx.x * 64;

    for (int i = threadIdx.x; i < 64 * 16; i += 256) {
        int r = i >> 4;
        int q = i & 15;
        int n = n0 + r;
        uint4 u = make_uint4(0u, 0u, 0u, 0u);
        if (n < N) u = agg_bf4[(size_t)n * 16 + q];
        float4 f0, f1;
        f0.x = __uint_as_float(u.x << 16);
        f0.y = __uint_as_float(u.x & 0xFFFF0000u);
        f0.z = __uint_as_float(u.y << 16);
        f0.w = __uint_as_float(u.y & 0xFFFF0000u);
        f1.x = __uint_as_float(u.z << 16);
        f1.y = __uint_as_float(u.z & 0xFFFF0000u);
        f1.z = __uint_as_float(u.w << 16);
        f1.w = __uint_as_float(u.w & 0xFFFF0000u);
        int m = (r >> 2) & 7;
        ((float4*)aggS)[r * 32 + ((2 * q) ^ m)] = f0;
        ((float4*)aggS)[r * 32 + ((2 * q + 1) ^ m)] = f1;
    }

    const int tc = threadIdx.x & 15;
    const int tr = threadIdx.x >> 4;

    float invd[4];
#pragma unroll
    for (int i = 0; i < 4; ++i) {
        int n = n0 + 4 * tr + i;
        float degf = 1.0f;
        if (n < N) degf = fmaxf((float)(off[n + 1] - off[n]), 1.0f);
        invd[i] = 1.0f / degf;
    }

    for (int h = 0; h < 2; ++h) {
        for (int i = threadIdx.x; i < 128 * 16; i += 256) {
            int k = i >> 4;
            int j4 = i & 15;
            ((float4*)Ws)[k * 16 + j4] = ((const float4*)Wm)[k * 32 + h * 16 + j4];
        }
        __syncthreads();

        float acc[4][4];
#pragma unroll
        for (int i = 0; i < 4; ++i)
#pragma unroll
            for (int c = 0; c < 4; ++c) acc[i][c] = 0.f;

#pragma unroll 4
        for (int k0 = 0; k0 < 128; k0 += 4) {
            float4 ar4[4];
            const int chunk = (k0 >> 2) ^ (tr & 7);
#pragma unroll
            for (int i = 0; i < 4; ++i) {
                int r = 4 * tr + i;
                ar4[i] = ((const float4*)aggS)[r * 32 + chunk];
            }
            float4 wv4[4];
#pragma unroll
            for (int kk = 0; kk < 4; ++kk)
                wv4[kk] = *(const float4*)&Ws[(k0 + kk) * 64 + tc * 4];

            float wvv[4][4];
#pragma unroll
            for (int kk = 0; kk < 4; ++kk) {
                wvv[kk][0] = wv4[kk].x; wvv[kk][1] = wv4[kk].y;
                wvv[kk][2] = wv4[kk].z; wvv[kk][3] = wv4[kk].w;
            }
#pragma unroll
            for (int i = 0; i < 4; ++i) {
                float av[4] = {ar4[i].x, ar4[i].y, ar4[i].z, ar4[i].w};
#pragma unroll
                for (int kk = 0; kk < 4; ++kk)
#pragma unroll
                    for (int c = 0; c < 4; ++c)
                        acc[i][c] = fmaf(av[kk], wvv[kk][c], acc[i][c]);
            }
        }

#pragma unroll
        for (int i = 0; i < 4; ++i) {
            int n = n0 + 4 * tr + i;
            if (n < N) {
                size_t base = (size_t)n * FEAT + h * 64 + tc * 4;
                float4 xv = *(const float4*)&x[base];
                float4 o;
                o.x = xv.x + invd[i] * acc[i][0];
                o.y = xv.y + invd[i] * acc[i][1];
                o.z = xv.z + invd[i] * acc[i][2];
                o.w = xv.w + invd[i] * acc[i][3];
                *(float4*)&out[base] = o;
            }
        }
        __syncthreads();
    }
}

// ---------------- fallback (atomic path) ---------------
__global__ __launch_bounds__(256) void scatter_fallback(
    const float4* __restrict__ x4, const int* __restrict__ sender,
    const int* __restrict__ receiver, const float* __restrict__ edge_len,
    const float* __restrict__ log_scale, const float* __restrict__ filter_w,
    const float* __restrict__ filter_b, float* __restrict__ agg,
    float* __restrict__ deg, int E) {
    int gid = blockIdx.x * 256 + threadIdx.x;
    int e = gid >> 5;
    if (e >= E) return;
    int lane = gid & 31;
    int s = sender[e];
    int r = receiver[e];
    float scale = expf(log_scale[0]) + 1e-6f;
    float w = edge_weight(edge_len[e], scale, filter_w[0], filter_b[0]);
    float4 xv = x4[s * (FEAT / 4) + lane];
    float* dst = agg + (size_t)r * FEAT + lane * 4;
    unsafeAtomicAdd(dst + 0, w * xv.x);
    unsafeAtomicAdd(dst + 1, w * xv.y);
    unsafeAtomicAdd(dst + 2, w * xv.z);
    unsafeAtomicAdd(dst + 3, w * xv.w);
    if (lane == 0) unsafeAtomicAdd(&deg[r], 1.0f);
}

__global__ __launch_bounds__(256) void finalize_fallback(
    const float* __restrict__ x, const float* __restrict__ agg,
    const float* __restrict__ deg, const float* __restrict__ Wm,
    float* __restrict__ out, int N) {
    __shared__ float Wsf[FEAT * FEAT];
    for (int i = threadIdx.x * 4; i < FEAT * FEAT; i += 256 * 4)
        *(float4*)&Wsf[i] = *(const float4*)&Wm[i];
    __syncthreads();
    int half = threadIdx.x >> 7;
    int j = threadIdx.x & (FEAT - 1);
    for (int n0 = blockIdx.x * 2; n0 < N; n0 += gridDim.x * 2) {
        int n = n0 + half;
        if (n < N) {
            const float* arow = agg + (size_t)n * FEAT;
            float acc = 0.0f;
#pragma unroll 16
            for (int k = 0; k < FEAT; ++k) acc = fmaf(arow[k], Wsf[k * FEAT + j], acc);
            float invd = 1.0f / fmaxf(deg[n], 1.0f);
            size_t idx = (size_t)n * FEAT + j;
            out[idx] = x[idx] + invd * acc;
        }
    }
}

extern "C" void kernel_launch(void* const* d_in, const int* in_sizes, int n_in,
                              void* d_out, int out_size, void* d_ws, size_t ws_size,
                              hipStream_t stream) {
    const float* x         = (const float*)d_in[0];
    const int*   ei        = (const int*)d_in[1];
    const float* edge_len  = (const float*)d_in[2];
    const float* W_mix     = (const float*)d_in[3];
    const float* log_scale = (const float*)d_in[4];
    const float* filter_w  = (const float*)d_in[5];
    const float* filter_b  = (const float*)d_in[6];
    float* out = (float*)d_out;

    const int N = in_sizes[0] / FEAT;
    const int E = in_sizes[1] / 2;
    const int* sender   = ei;
    const int* receiver = ei + E;
    const int nbuck = (N + BNODES - 1) >> BSHIFT;

    // ws layout: xbf [N*128 bf16], agg_bf [N*128 bf16], buf [E*8],
    // off [(N+1)*4], bcur [nbuck*4]  -> ~37.8 MB
    size_t xbf_bytes  = (size_t)N * FEAT * 2;
    size_t aggb_bytes = (size_t)N * FEAT * 2;
    size_t buf_bytes  = (size_t)E * 8;
    size_t off_bytes  = (((size_t)(N + 1) * 4) + 63) & ~(size_t)63;
    size_t bcur_bytes = (((size_t)nbuck * 4) + 63) & ~(size_t)63;
    size_t needed = xbf_bytes + aggb_bytes + buf_bytes + off_bytes + bcur_bytes;

    if (ws_size >= needed && N <= 65536) {
        char* p = (char*)d_ws;
        uint2* xbf    = (uint2*)p;                       p += xbf_bytes;
        uint4* agg_bf = (uint4*)p;                       p += aggb_bytes;
        unsigned long long* buf = (unsigned long long*)p; p += buf_bytes;
        int* off  = (int*)p;                             p += off_bytes;
        int* bcur = (int*)p;

        hipMemsetAsync(off, 0, (size_t)(N + 1) * 4, stream);

        int cblocks = (N * (FEAT / 4) + 255) / 256;
        convert_kernel<<<cblocks, 256, 0, stream>>>((const float4*)x, xbf,
                                                    N * (FEAT / 4));
        int eblocks = (E + 255) / 256;
        hist_kernel<<<eblocks, 256, 0, stream>>>(receiver, off, E);
        scan_kernel<<<1, 1024, 0, stream>>>(off, N);
        bcur_init_kernel<<<(nbuck + 255) / 256, 256, 0, stream>>>(off, bcur, nbuck);
        bucket_scatter_kernel<<<eblocks, 256, 0, stream>>>(
            sender, receiver, edge_len, log_scale, filter_w, filter_b,
            bcur, buf, E);
        bucket_aggregate_kernel<<<nbuck, 256, 0, stream>>>(
            (const uint4*)xbf, buf, off, agg_bf, N);
        int fblocks = (N + 63) / 64;
        finalize_kernel<<<fblocks, 256, 0, stream>>>(x, (const uint4*)agg_bf, off,
                                                     W_mix, out, N);
    } else {
        float* agg = (float*)d_ws;
        float* deg = agg + (size_t)N * FEAT;
        hipMemsetAsync(agg, 0, ((size_t)N * FEAT + N) * sizeof(float), stream);
        int sblocks = (E * 32 + 255) / 256;
        scatter_fallback<<<sblocks, 256, 0, stream>>>(
            (const float4*)x, sender, receiver, edge_len,
            log_scale, filter_w, filter_b, agg, deg, E);
        finalize_fallback<<<512, 256, 0, stream>>>(x, agg, deg, W_mix, out, N);
    }
}

// Round 6
// 640.942 us; speedup vs baseline: 2.5118x; 2.5118x over previous
//
#include <hip/hip_runtime.h>
#include <math.h>

#define FEAT 128
#define BSHIFT 5            // 32 nodes per bucket
#define BNODES 32
#define CAP 2048            // records per sort chunk (16 KB LDS)

__device__ __forceinline__ float edge_weight(float d, float scale, float fw, float fb) {
    // scale already includes +1e-6
    float t = fmaxf(d / scale, 0.0f);
    float decay = expf(-t * t);
    float g = 1.0f / (1.0f + expf(-(d * fw + fb)));
    float w = decay * g;
    if (!isfinite(w)) w = 0.0f;
    return w;
}

__device__ __forceinline__ unsigned int bf16_rne(float f) {
    unsigned int b = __float_as_uint(f);
    return (b + 0x7FFFu + ((b >> 16) & 1u)) >> 16;
}

// ---------------- x -> bf16 table ----------------
__global__ __launch_bounds__(256) void convert_kernel(const float4* __restrict__ x4,
                                                      uint2* __restrict__ xbf,
                                                      int n4) {
    int i = blockIdx.x * 256 + threadIdx.x;
    if (i >= n4) return;
    float4 v = x4[i];
    uint2 o;
    o.x = (bf16_rne(v.y) << 16) | bf16_rne(v.x);
    o.y = (bf16_rne(v.w) << 16) | bf16_rne(v.z);
    xbf[i] = o;
}

// ---------------- per-BUCKET histogram + scan + cursor init ----------------
__global__ __launch_bounds__(256) void hist_kernel(const int* __restrict__ recv,
                                                   int* __restrict__ boff, int E) {
    int e = blockIdx.x * 256 + threadIdx.x;
    if (e < E) atomicAdd(&boff[(recv[e] >> BSHIFT) + 1], 1);
}

__global__ __launch_bounds__(1024) void scan_kernel(int* __restrict__ off, int M) {
    __shared__ int part[1024];
    int t = threadIdx.x;
    int chunk = (M + 1023) >> 10;
    int lo = t * chunk, hi = min(lo + chunk, M);
    int s = 0;
    for (int i = lo; i < hi; ++i) s += off[1 + i];
    part[t] = s;
    __syncthreads();
    for (int d = 1; d < 1024; d <<= 1) {
        int v = (t >= d) ? part[t - d] : 0;
        __syncthreads();
        part[t] += v;
        __syncthreads();
    }
    int run = part[t] - s;
    for (int i = lo; i < hi; ++i) {
        run += off[1 + i];
        off[1 + i] = run;
    }
    if (t == 0) off[0] = 0;
}

__global__ __launch_bounds__(256) void bcur_init_kernel(const int* __restrict__ boff,
                                                        int* __restrict__ bcur,
                                                        int nbuck) {
    int b = blockIdx.x * 256 + threadIdx.x;
    if (b < nbuck) bcur[b] = boff[b];
}

// ---------------- bucket scatter: 8B record {w | local<<16 | sender} --------
__global__ __launch_bounds__(256) void bucket_scatter_kernel(
    const int* __restrict__ sender, const int* __restrict__ recv,
    const float* __restrict__ edge_len,
    const float* __restrict__ log_scale, const float* __restrict__ filter_w,
    const float* __restrict__ filter_b,
    int* __restrict__ bcur, unsigned long long* __restrict__ buf, int E) {
    int e = blockIdx.x * 256 + threadIdx.x;
    if (e >= E) return;
    float scale = expf(log_scale[0]) + 1e-6f;
    float w = edge_weight(edge_len[e], scale, filter_w[0], filter_b[0]);
    int r = recv[e];
    int s = sender[e];
    int pos = atomicAdd(&bcur[r >> BSHIFT], 1);
    unsigned long long rec = ((unsigned long long)__float_as_uint(w) << 32)
                           | (unsigned int)(s & 0xFFFF)
                           | ((unsigned int)(r & (BNODES - 1)) << 16);
    buf[pos] = rec;
}

// ---------------- sort+aggregate: counting sort in LDS, register accumulate -
// One block per bucket. Chunked: load <=CAP records to registers, rank via 32
// LDS counters (1 atomic per record), scan, scatter sorted into LDS. Then each
// 16-lane group walks its 2 nodes' contiguous segments: LDS broadcast record +
// 16-lane bf16 gather + 8 register FMAs. Degree = summed counts.
__device__ __forceinline__ void accum8(float acc[8], uint4 u, float w) {
    acc[0] = fmaf(w, __uint_as_float(u.x << 16), acc[0]);
    acc[1] = fmaf(w, __uint_as_float(u.x & 0xFFFF0000u), acc[1]);
    acc[2] = fmaf(w, __uint_as_float(u.y << 16), acc[2]);
    acc[3] = fmaf(w, __uint_as_float(u.y & 0xFFFF0000u), acc[3]);
    acc[4] = fmaf(w, __uint_as_float(u.z << 16), acc[4]);
    acc[5] = fmaf(w, __uint_as_float(u.z & 0xFFFF0000u), acc[5]);
    acc[6] = fmaf(w, __uint_as_float(u.w << 16), acc[6]);
    acc[7] = fmaf(w, __uint_as_float(u.w & 0xFFFF0000u), acc[7]);
}

__global__ __launch_bounds__(256) void bucket_sort_aggregate_kernel(
    const uint4* __restrict__ xbf4, const unsigned long long* __restrict__ buf,
    const int* __restrict__ boff, uint4* __restrict__ agg_bf4,
    int* __restrict__ deg, int N) {
    __shared__ unsigned long long recS[CAP];   // 16 KB
    __shared__ int cnt32[BNODES];
    __shared__ int segoff[BNODES + 1];

    int b = blockIdx.x;
    int n0 = b << BSHIFT;
    int nEnd = min(n0 + BNODES, N);
    int lo = boff[b], hi = boff[b + 1];
    int tid = threadIdx.x;
    int lane = tid & 15;
    int grp = tid >> 4;

    float acc[2][8] = {{0.f,0.f,0.f,0.f,0.f,0.f,0.f,0.f},
                       {0.f,0.f,0.f,0.f,0.f,0.f,0.f,0.f}};
    int dcnt[2] = {0, 0};

    for (int pos = lo; pos < hi; pos += CAP) {
        int cnt = min(CAP, hi - pos);
        if (tid < BNODES) cnt32[tid] = 0;
        __syncthreads();

        unsigned long long rec[CAP / 256];
        int rnk[CAP / 256];
        int locl[CAP / 256];
#pragma unroll
        for (int k = 0; k < CAP / 256; ++k) {
            int i = k * 256 + tid;
            if (i < cnt) {
                unsigned long long r = buf[pos + i];
                int l = ((unsigned int)r >> 16) & (BNODES - 1);
                rec[k] = r;
                locl[k] = l;
                rnk[k] = atomicAdd(&cnt32[l], 1);
            }
        }
        __syncthreads();
        if (tid == 0) {
            int run = 0;
#pragma unroll
            for (int l = 0; l < BNODES; ++l) { segoff[l] = run; run += cnt32[l]; }
            segoff[BNODES] = run;
        }
        __syncthreads();
#pragma unroll
        for (int k = 0; k < CAP / 256; ++k) {
            int i = k * 256 + tid;
            if (i < cnt) recS[segoff[locl[k]] + rnk[k]] = rec[k];
        }
        __syncthreads();

        // accumulate: group handles local nodes grp and grp+16
#pragma unroll
        for (int which = 0; which < 2; ++which) {
            int l = grp + which * 16;
            int s0 = segoff[l], s1 = segoff[l + 1];
            dcnt[which] += s1 - s0;
            int i = s0;
            for (; i + 2 <= s1; i += 2) {
                unsigned long long ra = recS[i];
                unsigned long long rb = recS[i + 1];
                float wa = __uint_as_float((unsigned int)(ra >> 32));
                float wb = __uint_as_float((unsigned int)(rb >> 32));
                int sa = (unsigned int)ra & 0xFFFF;
                int sb = (unsigned int)rb & 0xFFFF;
                uint4 ua = xbf4[(size_t)sa * 16 + lane];
                uint4 ub = xbf4[(size_t)sb * 16 + lane];
                accum8(acc[which], ua, wa);
                accum8(acc[which], ub, wb);
            }
            if (i < s1) {
                unsigned long long ra = recS[i];
                float wa = __uint_as_float((unsigned int)(ra >> 32));
                int sa = (unsigned int)ra & 0xFFFF;
                uint4 ua = xbf4[(size_t)sa * 16 + lane];
                accum8(acc[which], ua, wa);
            }
        }
        __syncthreads();   // before next chunk overwrites recS
    }

    // writeout: bf16-pack; lane owns features lane*8..lane*8+7
#pragma unroll
    for (int which = 0; which < 2; ++which) {
        int n = n0 + grp + which * 16;
        if (n < nEnd) {
            uint4 o;
            o.x = (bf16_rne(acc[which][1]) << 16) | bf16_rne(acc[which][0]);
            o.y = (bf16_rne(acc[which][3]) << 16) | bf16_rne(acc[which][2]);
            o.z = (bf16_rne(acc[which][5]) << 16) | bf16_rne(acc[which][4]);
            o.w = (bf16_rne(acc[which][7]) << 16) | bf16_rne(acc[which][6]);
            agg_bf4[(size_t)n * 16 + lane] = o;
            if (lane == 0) deg[n] = dcnt[which];
        }
    }
}

// ---------------- finalize: tiled GEMM, out = x + (agg/deg) @ W --------------
__global__ __launch_bounds__(256) void finalize_kernel(
    const float* __restrict__ x, const uint4* __restrict__ agg_bf4,
    const int* __restrict__ deg, const float* __restrict__ Wm,
    float* __restrict__ out, int N) {
    __shared__ float aggS[64 * 128];  // 32 KB
    __shared__ float Ws[128 * 64];    // 32 KB
    const int n0 = blockIdx.x * 64;

    for (int i = threadIdx.x; i < 64 * 16; i += 256) {
        int r = i >> 4;
        int q = i & 15;
        int n = n0 + r;
        uint4 u = make_uint4(0u, 0u, 0u, 0u);
        if (n < N) u = agg_bf4[(size_t)n * 16 + q];
        float4 f0, f1;
        f0.x = __uint_as_float(u.x << 16);
        f0.y = __uint_as_float(u.x & 0xFFFF0000u);
        f0.z = __uint_as_float(u.y << 16);
        f0.w = __uint_as_float(u.y & 0xFFFF0000u);
        f1.x = __uint_as_float(u.z << 16);
        f1.y = __uint_as_float(u.z & 0xFFFF0000u);
        f1.z = __uint_as_float(u.w << 16);
        f1.w = __uint_as_float(u.w & 0xFFFF0000u);
        int m = (r >> 2) & 7;
        ((float4*)aggS)[r * 32 + ((2 * q) ^ m)] = f0;
        ((float4*)aggS)[r * 32 + ((2 * q + 1) ^ m)] = f1;
    }

    const int tc = threadIdx.x & 15;
    const int tr = threadIdx.x >> 4;

    float invd[4];
#pragma unroll
    for (int i = 0; i < 4; ++i) {
        int n = n0 + 4 * tr + i;
        float degf = 1.0f;
        if (n < N) degf = fmaxf((float)deg[n], 1.0f);
        invd[i] = 1.0f / degf;
    }

    for (int h = 0; h < 2; ++h) {
        for (int i = threadIdx.x; i < 128 * 16; i += 256) {
            int k = i >> 4;
            int j4 = i & 15;
            ((float4*)Ws)[k * 16 + j4] = ((const float4*)Wm)[k * 32 + h * 16 + j4];
        }
        __syncthreads();

        float acc[4][4];
#pragma unroll
        for (int i = 0; i < 4; ++i)
#pragma unroll
            for (int c = 0; c < 4; ++c) acc[i][c] = 0.f;

#pragma unroll 4
        for (int k0 = 0; k0 < 128; k0 += 4) {
            float4 ar4[4];
            const int chunk = (k0 >> 2) ^ (tr & 7);
#pragma unroll
            for (int i = 0; i < 4; ++i) {
                int r = 4 * tr + i;
                ar4[i] = ((const float4*)aggS)[r * 32 + chunk];
            }
            float4 wv4[4];
#pragma unroll
            for (int kk = 0; kk < 4; ++kk)
                wv4[kk] = *(const float4*)&Ws[(k0 + kk) * 64 + tc * 4];

            float wvv[4][4];
#pragma unroll
            for (int kk = 0; kk < 4; ++kk) {
                wvv[kk][0] = wv4[kk].x; wvv[kk][1] = wv4[kk].y;
                wvv[kk][2] = wv4[kk].z; wvv[kk][3] = wv4[kk].w;
            }
#pragma unroll
            for (int i = 0; i < 4; ++i) {
                float av[4] = {ar4[i].x, ar4[i].y, ar4[i].z, ar4[i].w};
#pragma unroll
                for (int kk = 0; kk < 4; ++kk)
#pragma unroll
                    for (int c = 0; c < 4; ++c)
                        acc[i][c] = fmaf(av[kk], wvv[kk][c], acc[i][c]);
            }
        }

#pragma unroll
        for (int i = 0; i < 4; ++i) {
            int n = n0 + 4 * tr + i;
            if (n < N) {
                size_t base = (size_t)n * FEAT + h * 64 + tc * 4;
                float4 xv = *(const float4*)&x[base];
                float4 o;
                o.x = xv.x + invd[i] * acc[i][0];
                o.y = xv.y + invd[i] * acc[i][1];
                o.z = xv.z + invd[i] * acc[i][2];
                o.w = xv.w + invd[i] * acc[i][3];
                *(float4*)&out[base] = o;
            }
        }
        __syncthreads();
    }
}

// ---------------- fallback (atomic path) ---------------
__global__ __launch_bounds__(256) void scatter_fallback(
    const float4* __restrict__ x4, const int* __restrict__ sender,
    const int* __restrict__ receiver, const float* __restrict__ edge_len,
    const float* __restrict__ log_scale, const float* __restrict__ filter_w,
    const float* __restrict__ filter_b, float* __restrict__ agg,
    float* __restrict__ deg, int E) {
    int gid = blockIdx.x * 256 + threadIdx.x;
    int e = gid >> 5;
    if (e >= E) return;
    int lane = gid & 31;
    int s = sender[e];
    int r = receiver[e];
    float scale = expf(log_scale[0]) + 1e-6f;
    float w = edge_weight(edge_len[e], scale, filter_w[0], filter_b[0]);
    float4 xv = x4[s * (FEAT / 4) + lane];
    float* dst = agg + (size_t)r * FEAT + lane * 4;
    unsafeAtomicAdd(dst + 0, w * xv.x);
    unsafeAtomicAdd(dst + 1, w * xv.y);
    unsafeAtomicAdd(dst + 2, w * xv.z);
    unsafeAtomicAdd(dst + 3, w * xv.w);
    if (lane == 0) unsafeAtomicAdd(&deg[r], 1.0f);
}

__global__ __launch_bounds__(256) void finalize_fallback(
    const float* __restrict__ x, const float* __restrict__ agg,
    const float* __restrict__ deg, const float* __restrict__ Wm,
    float* __restrict__ out, int N) {
    __shared__ float Wsf[FEAT * FEAT];
    for (int i = threadIdx.x * 4; i < FEAT * FEAT; i += 256 * 4)
        *(float4*)&Wsf[i] = *(const float4*)&Wm[i];
    __syncthreads();
    int half = threadIdx.x >> 7;
    int j = threadIdx.x & (FEAT - 1);
    for (int n0 = blockIdx.x * 2; n0 < N; n0 += gridDim.x * 2) {
        int n = n0 + half;
        if (n < N) {
            const float* arow = agg + (size_t)n * FEAT;
            float acc = 0.0f;
#pragma unroll 16
            for (int k = 0; k < FEAT; ++k) acc = fmaf(arow[k], Wsf[k * FEAT + j], acc);
            float invd = 1.0f / fmaxf(deg[n], 1.0f);
            size_t idx = (size_t)n * FEAT + j;
            out[idx] = x[idx] + invd * acc;
        }
    }
}

extern "C" void kernel_launch(void* const* d_in, const int* in_sizes, int n_in,
                              void* d_out, int out_size, void* d_ws, size_t ws_size,
                              hipStream_t stream) {
    const float* x         = (const float*)d_in[0];
    const int*   ei        = (const int*)d_in[1];
    const float* edge_len  = (const float*)d_in[2];
    const float* W_mix     = (const float*)d_in[3];
    const float* log_scale = (const float*)d_in[4];
    const float* filter_w  = (const float*)d_in[5];
    const float* filter_b  = (const float*)d_in[6];
    float* out = (float*)d_out;

    const int N = in_sizes[0] / FEAT;
    const int E = in_sizes[1] / 2;
    const int* sender   = ei;
    const int* receiver = ei + E;
    const int nbuck = (N + BNODES - 1) >> BSHIFT;

    // ws layout: xbf [N*128 bf16], agg_bf [N*128 bf16], buf [E*8],
    // boff [(nbuck+1)*4], bcur [nbuck*4], deg [N*4]  -> ~37.8 MB
    size_t xbf_bytes  = (size_t)N * FEAT * 2;
    size_t aggb_bytes = (size_t)N * FEAT * 2;
    size_t buf_bytes  = (size_t)E * 8;
    size_t boff_bytes = (((size_t)(nbuck + 1) * 4) + 63) & ~(size_t)63;
    size_t bcur_bytes = (((size_t)nbuck * 4) + 63) & ~(size_t)63;
    size_t deg_bytes  = (((size_t)N * 4) + 63) & ~(size_t)63;
    size_t needed = xbf_bytes + aggb_bytes + buf_bytes + boff_bytes +
                    bcur_bytes + deg_bytes;

    if (ws_size >= needed && N <= 65536) {
        char* p = (char*)d_ws;
        uint2* xbf    = (uint2*)p;                        p += xbf_bytes;
        uint4* agg_bf = (uint4*)p;                        p += aggb_bytes;
        unsigned long long* buf = (unsigned long long*)p; p += buf_bytes;
        int* boff = (int*)p;                              p += boff_bytes;
        int* bcur = (int*)p;                              p += bcur_bytes;
        int* deg  = (int*)p;

        hipMemsetAsync(boff, 0, (size_t)(nbuck + 1) * 4, stream);

        int cblocks = (N * (FEAT / 4) + 255) / 256;
        convert_kernel<<<cblocks, 256, 0, stream>>>((const float4*)x, xbf,
                                                    N * (FEAT / 4));
        int eblocks = (E + 255) / 256;
        hist_kernel<<<eblocks, 256, 0, stream>>>(receiver, boff, E);
        scan_kernel<<<1, 1024, 0, stream>>>(boff, nbuck);
        bcur_init_kernel<<<(nbuck + 255) / 256, 256, 0, stream>>>(boff, bcur, nbuck);
        bucket_scatter_kernel<<<eblocks, 256, 0, stream>>>(
            sender, receiver, edge_len, log_scale, filter_w, filter_b,
            bcur, buf, E);
        bucket_sort_aggregate_kernel<<<nbuck, 256, 0, stream>>>(
            (const uint4*)xbf, buf, boff, agg_bf, deg, N);
        int fblocks = (N + 63) / 64;
        finalize_kernel<<<fblocks, 256, 0, stream>>>(x, (const uint4*)agg_bf, deg,
                                                     W_mix, out, N);
    } else {
        float* agg = (float*)d_ws;
        float* degf = agg + (size_t)N * FEAT;
        hipMemsetAsync(agg, 0, ((size_t)N * FEAT + N) * sizeof(float), stream);
        int sblocks = (E * 32 + 255) / 256;
        scatter_fallback<<<sblocks, 256, 0, stream>>>(
            (const float4*)x, sender, receiver, edge_len,
            log_scale, filter_w, filter_b, agg, degf, E);
        finalize_fallback<<<512, 256, 0, stream>>>(x, agg, degf, W_mix, out, N);
    }
}

// Round 7
// 245.045 us; speedup vs baseline: 6.5699x; 2.6156x over previous
//
#include <hip/hip_runtime.h>
#include <math.h>

#define FEAT 128
#define BSHIFT 5            // 32 nodes per bucket
#define BNODES 32
#define CAP 2048            // records per sort chunk (16 KB LDS)
#define EPB 8192            // edges per block in count/scatter
#define NBUCK_MAX 2048      // N <= 65536

__device__ __forceinline__ float edge_weight(float d, float scale, float fw, float fb) {
    // scale already includes +1e-6
    float t = fmaxf(d / scale, 0.0f);
    float decay = expf(-t * t);
    float g = 1.0f / (1.0f + expf(-(d * fw + fb)));
    float w = decay * g;
    if (!isfinite(w)) w = 0.0f;
    return w;
}

__device__ __forceinline__ unsigned int bf16_rne(float f) {
    unsigned int b = __float_as_uint(f);
    return (b + 0x7FFFu + ((b >> 16) & 1u)) >> 16;
}

// ---------------- x -> bf16 table ----------------
__global__ __launch_bounds__(256) void convert_kernel(const float4* __restrict__ x4,
                                                      uint2* __restrict__ xbf,
                                                      int n4) {
    int i = blockIdx.x * 256 + threadIdx.x;
    if (i >= n4) return;
    float4 v = x4[i];
    uint2 o;
    o.x = (bf16_rne(v.y) << 16) | bf16_rne(v.x);
    o.y = (bf16_rne(v.w) << 16) | bf16_rne(v.z);
    xbf[i] = o;
}

// ---------------- count: block-local LDS histogram -> few global atomics ----
__global__ __launch_bounds__(256) void count_kernel(const int* __restrict__ recv,
                                                    int* __restrict__ boff,
                                                    int E, int nbuck) {
    __shared__ int cnt[NBUCK_MAX];
    int tid = threadIdx.x;
    for (int i = tid; i < nbuck; i += 256) cnt[i] = 0;
    __syncthreads();
    int base = blockIdx.x * EPB;
    int end = min(base + EPB, E);
    for (int e = base + tid; e < end; e += 256)
        atomicAdd(&cnt[recv[e] >> BSHIFT], 1);
    __syncthreads();
    for (int i = tid; i < nbuck; i += 256) {
        int c = cnt[i];
        if (c) atomicAdd(&boff[i + 1], c);   // no return needed: fire-and-forget
    }
}

// ---------------- scan over bucket counts; also writes bcur bases ----------
__global__ __launch_bounds__(1024) void scan_kernel(int* __restrict__ off,
                                                    int* __restrict__ bcur, int M) {
    __shared__ int part[1024];
    int t = threadIdx.x;
    int chunk = (M + 1023) >> 10;
    int lo = t * chunk, hi = min(lo + chunk, M);
    int s = 0;
    for (int i = lo; i < hi; ++i) s += off[1 + i];
    part[t] = s;
    __syncthreads();
    for (int d = 1; d < 1024; d <<= 1) {
        int v = (t >= d) ? part[t - d] : 0;
        __syncthreads();
        part[t] += v;
        __syncthreads();
    }
    int run = part[t] - s;
    for (int i = lo; i < hi; ++i) {
        bcur[i] = run;          // base of bucket i
        run += off[1 + i];
        off[1 + i] = run;       // inclusive -> CSR offset for bucket i+1
    }
    if (t == 0) off[0] = 0;
}

// ---------------- scatter: LDS binning, one reserve atomic per (block,bucket)
// Pass A: count chunk's edges per bucket in LDS. Reserve: one returning global
// atomicAdd per nonempty bucket -> LDS cursor = global base. Pass B: per-edge
// position from LDS atomic, write 8B record {w | local<<16 | sender}.
__global__ __launch_bounds__(256) void bucket_scatter_kernel(
    const int* __restrict__ sender, const int* __restrict__ recv,
    const float* __restrict__ edge_len,
    const float* __restrict__ log_scale, const float* __restrict__ filter_w,
    const float* __restrict__ filter_b,
    int* __restrict__ bcur, unsigned long long* __restrict__ buf,
    int E, int nbuck) {
    __shared__ int cur[NBUCK_MAX];
    int tid = threadIdx.x;
    for (int i = tid; i < nbuck; i += 256) cur[i] = 0;
    __syncthreads();
    int base = blockIdx.x * EPB;
    int end = min(base + EPB, E);
    for (int e = base + tid; e < end; e += 256)
        atomicAdd(&cur[recv[e] >> BSHIFT], 1);
    __syncthreads();
    for (int i = tid; i < nbuck; i += 256) {
        int c = cur[i];
        cur[i] = c ? atomicAdd(&bcur[i], c) : 0;  // reserve contiguous run
    }
    __syncthreads();
    float scale = expf(log_scale[0]) + 1e-6f;
    float fw = filter_w[0], fb = filter_b[0];
    for (int e = base + tid; e < end; e += 256) {
        int r = recv[e];
        int s = sender[e];
        float w = edge_weight(edge_len[e], scale, fw, fb);
        int pos = atomicAdd(&cur[r >> BSHIFT], 1);
        unsigned long long rec = ((unsigned long long)__float_as_uint(w) << 32)
                               | (unsigned int)(s & 0xFFFF)
                               | ((unsigned int)(r & (BNODES - 1)) << 16);
        buf[pos] = rec;
    }
}

// ---------------- sort+aggregate: counting sort in LDS, register accumulate -
__device__ __forceinline__ void accum8(float acc[8], uint4 u, float w) {
    acc[0] = fmaf(w, __uint_as_float(u.x << 16), acc[0]);
    acc[1] = fmaf(w, __uint_as_float(u.x & 0xFFFF0000u), acc[1]);
    acc[2] = fmaf(w, __uint_as_float(u.y << 16), acc[2]);
    acc[3] = fmaf(w, __uint_as_float(u.y & 0xFFFF0000u), acc[3]);
    acc[4] = fmaf(w, __uint_as_float(u.z << 16), acc[4]);
    acc[5] = fmaf(w, __uint_as_float(u.z & 0xFFFF0000u), acc[5]);
    acc[6] = fmaf(w, __uint_as_float(u.w << 16), acc[6]);
    acc[7] = fmaf(w, __uint_as_float(u.w & 0xFFFF0000u), acc[7]);
}

__global__ __launch_bounds__(256) void bucket_sort_aggregate_kernel(
    const uint4* __restrict__ xbf4, const unsigned long long* __restrict__ buf,
    const int* __restrict__ boff, uint4* __restrict__ agg_bf4,
    int* __restrict__ deg, int N) {
    __shared__ unsigned long long recS[CAP];   // 16 KB
    __shared__ int cnt32[BNODES];
    __shared__ int segoff[BNODES + 1];

    int b = blockIdx.x;
    int n0 = b << BSHIFT;
    int nEnd = min(n0 + BNODES, N);
    int lo = boff[b], hi = boff[b + 1];
    int tid = threadIdx.x;
    int lane = tid & 15;
    int grp = tid >> 4;

    float acc[2][8] = {{0.f,0.f,0.f,0.f,0.f,0.f,0.f,0.f},
                       {0.f,0.f,0.f,0.f,0.f,0.f,0.f,0.f}};
    int dcnt[2] = {0, 0};

    for (int pos = lo; pos < hi; pos += CAP) {
        int cnt = min(CAP, hi - pos);
        if (tid < BNODES) cnt32[tid] = 0;
        __syncthreads();

        unsigned long long rec[CAP / 256];
        int rnk[CAP / 256];
        int locl[CAP / 256];
#pragma unroll
        for (int k = 0; k < CAP / 256; ++k) {
            int i = k * 256 + tid;
            if (i < cnt) {
                unsigned long long r = buf[pos + i];
                int l = ((unsigned int)r >> 16) & (BNODES - 1);
                rec[k] = r;
                locl[k] = l;
                rnk[k] = atomicAdd(&cnt32[l], 1);
            }
        }
        __syncthreads();
        if (tid == 0) {
            int run = 0;
#pragma unroll
            for (int l = 0; l < BNODES; ++l) { segoff[l] = run; run += cnt32[l]; }
            segoff[BNODES] = run;
        }
        __syncthreads();
#pragma unroll
        for (int k = 0; k < CAP / 256; ++k) {
            int i = k * 256 + tid;
            if (i < cnt) recS[segoff[locl[k]] + rnk[k]] = rec[k];
        }
        __syncthreads();

        // accumulate: group handles local nodes grp and grp+16; 4-deep unroll
        // for more outstanding gathers (IF$-latency-bound)
#pragma unroll
        for (int which = 0; which < 2; ++which) {
            int l = grp + which * 16;
            int s0 = segoff[l], s1 = segoff[l + 1];
            dcnt[which] += s1 - s0;
            int i = s0;
            for (; i + 4 <= s1; i += 4) {
                unsigned long long r0 = recS[i];
                unsigned long long r1 = recS[i + 1];
                unsigned long long r2 = recS[i + 2];
                unsigned long long r3 = recS[i + 3];
                float w0 = __uint_as_float((unsigned int)(r0 >> 32));
                float w1 = __uint_as_float((unsigned int)(r1 >> 32));
                float w2 = __uint_as_float((unsigned int)(r2 >> 32));
                float w3 = __uint_as_float((unsigned int)(r3 >> 32));
                int s0i = (unsigned int)r0 & 0xFFFF;
                int s1i = (unsigned int)r1 & 0xFFFF;
                int s2i = (unsigned int)r2 & 0xFFFF;
                int s3i = (unsigned int)r3 & 0xFFFF;
                uint4 u0 = xbf4[(size_t)s0i * 16 + lane];
                uint4 u1 = xbf4[(size_t)s1i * 16 + lane];
                uint4 u2 = xbf4[(size_t)s2i * 16 + lane];
                uint4 u3 = xbf4[(size_t)s3i * 16 + lane];
                accum8(acc[which], u0, w0);
                accum8(acc[which], u1, w1);
                accum8(acc[which], u2, w2);
                accum8(acc[which], u3, w3);
            }
            for (; i < s1; ++i) {
                unsigned long long ra = recS[i];
                float wa = __uint_as_float((unsigned int)(ra >> 32));
                int sa = (unsigned int)ra & 0xFFFF;
                uint4 ua = xbf4[(size_t)sa * 16 + lane];
                accum8(acc[which], ua, wa);
            }
        }
        __syncthreads();   // before next chunk overwrites recS
    }

    // writeout: bf16-pack; lane owns features lane*8..lane*8+7
#pragma unroll
    for (int which = 0; which < 2; ++which) {
        int n = n0 + grp + which * 16;
        if (n < nEnd) {
            uint4 o;
            o.x = (bf16_rne(acc[which][1]) << 16) | bf16_rne(acc[which][0]);
            o.y = (bf16_rne(acc[which][3]) << 16) | bf16_rne(acc[which][2]);
            o.z = (bf16_rne(acc[which][5]) << 16) | bf16_rne(acc[which][4]);
            o.w = (bf16_rne(acc[which][7]) << 16) | bf16_rne(acc[which][6]);
            agg_bf4[(size_t)n * 16 + lane] = o;
            if (lane == 0) deg[n] = dcnt[which];
        }
    }
}

// ---------------- finalize: tiled GEMM, out = x + (agg/deg) @ W --------------
__global__ __launch_bounds__(256) void finalize_kernel(
    const float* __restrict__ x, const uint4* __restrict__ agg_bf4,
    const int* __restrict__ deg, const float* __restrict__ Wm,
    float* __restrict__ out, int N) {
    __shared__ float aggS[64 * 128];  // 32 KB
    __shared__ float Ws[128 * 64];    // 32 KB
    const int n0 = blockIdx.x * 64;

    for (int i = threadIdx.x; i < 64 * 16; i += 256) {
        int r = i >> 4;
        int q = i & 15;
        int n = n0 + r;
        uint4 u = make_uint4(0u, 0u, 0u, 0u);
        if (n < N) u = agg_bf4[(size_t)n * 16 + q];
        float4 f0, f1;
        f0.x = __uint_as_float(u.x << 16);
        f0.y = __uint_as_float(u.x & 0xFFFF0000u);
        f0.z = __uint_as_float(u.y << 16);
        f0.w = __uint_as_float(u.y & 0xFFFF0000u);
        f1.x = __uint_as_float(u.z << 16);
        f1.y = __uint_as_float(u.z & 0xFFFF0000u);
        f1.z = __uint_as_float(u.w << 16);
        f1.w = __uint_as_float(u.w & 0xFFFF0000u);
        int m = (r >> 2) & 7;
        ((float4*)aggS)[r * 32 + ((2 * q) ^ m)] = f0;
        ((float4*)aggS)[r * 32 + ((2 * q + 1) ^ m)] = f1;
    }

    const int tc = threadIdx.x & 15;
    const int tr = threadIdx.x >> 4;

    float invd[4];
#pragma unroll
    for (int i = 0; i < 4; ++i) {
        int n = n0 + 4 * tr + i;
        float degf = 1.0f;
        if (n < N) degf = fmaxf((float)deg[n], 1.0f);
        invd[i] = 1.0f / degf;
    }

    for (int h = 0; h < 2; ++h) {
        for (int i = threadIdx.x; i < 128 * 16; i += 256) {
            int k = i >> 4;
            int j4 = i & 15;
            ((float4*)Ws)[k * 16 + j4] = ((const float4*)Wm)[k * 32 + h * 16 + j4];
        }
        __syncthreads();

        float acc[4][4];
#pragma unroll
        for (int i = 0; i < 4; ++i)
#pragma unroll
            for (int c = 0; c < 4; ++c) acc[i][c] = 0.f;

#pragma unroll 4
        for (int k0 = 0; k0 < 128; k0 += 4) {
            float4 ar4[4];
            const int chunk = (k0 >> 2) ^ (tr & 7);
#pragma unroll
            for (int i = 0; i < 4; ++i) {
                int r = 4 * tr + i;
                ar4[i] = ((const float4*)aggS)[r * 32 + chunk];
            }
            float4 wv4[4];
#pragma unroll
            for (int kk = 0; kk < 4; ++kk)
                wv4[kk] = *(const float4*)&Ws[(k0 + kk) * 64 + tc * 4];

            float wvv[4][4];
#pragma unroll
            for (int kk = 0; kk < 4; ++kk) {
                wvv[kk][0] = wv4[kk].x; wvv[kk][1] = wv4[kk].y;
                wvv[kk][2] = wv4[kk].z; wvv[kk][3] = wv4[kk].w;
            }
#pragma unroll
            for (int i = 0; i < 4; ++i) {
                float av[4] = {ar4[i].x, ar4[i].y, ar4[i].z, ar4[i].w};
#pragma unroll
                for (int kk = 0; kk < 4; ++kk)
#pragma unroll
                    for (int c = 0; c < 4; ++c)
                        acc[i][c] = fmaf(av[kk], wvv[kk][c], acc[i][c]);
            }
        }

#pragma unroll
        for (int i = 0; i < 4; ++i) {
            int n = n0 + 4 * tr + i;
            if (n < N) {
                size_t base = (size_t)n * FEAT + h * 64 + tc * 4;
                float4 xv = *(const float4*)&x[base];
                float4 o;
                o.x = xv.x + invd[i] * acc[i][0];
                o.y = xv.y + invd[i] * acc[i][1];
                o.z = xv.z + invd[i] * acc[i][2];
                o.w = xv.w + invd[i] * acc[i][3];
                *(float4*)&out[base] = o;
            }
        }
        __syncthreads();
    }
}

// ---------------- fallback (atomic path) ---------------
__global__ __launch_bounds__(256) void scatter_fallback(
    const float4* __restrict__ x4, const int* __restrict__ sender,
    const int* __restrict__ receiver, const float* __restrict__ edge_len,
    const float* __restrict__ log_scale, const float* __restrict__ filter_w,
    const float* __restrict__ filter_b, float* __restrict__ agg,
    float* __restrict__ deg, int E) {
    int gid = blockIdx.x * 256 + threadIdx.x;
    int e = gid >> 5;
    if (e >= E) return;
    int lane = gid & 31;
    int s = sender[e];
    int r = receiver[e];
    float scale = expf(log_scale[0]) + 1e-6f;
    float w = edge_weight(edge_len[e], scale, filter_w[0], filter_b[0]);
    float4 xv = x4[s * (FEAT / 4) + lane];
    float* dst = agg + (size_t)r * FEAT + lane * 4;
    unsafeAtomicAdd(dst + 0, w * xv.x);
    unsafeAtomicAdd(dst + 1, w * xv.y);
    unsafeAtomicAdd(dst + 2, w * xv.z);
    unsafeAtomicAdd(dst + 3, w * xv.w);
    if (lane == 0) unsafeAtomicAdd(&deg[r], 1.0f);
}

__global__ __launch_bounds__(256) void finalize_fallback(
    const float* __restrict__ x, const float* __restrict__ agg,
    const float* __restrict__ deg, const float* __restrict__ Wm,
    float* __restrict__ out, int N) {
    __shared__ float Wsf[FEAT * FEAT];
    for (int i = threadIdx.x * 4; i < FEAT * FEAT; i += 256 * 4)
        *(float4*)&Wsf[i] = *(const float4*)&Wm[i];
    __syncthreads();
    int half = threadIdx.x >> 7;
    int j = threadIdx.x & (FEAT - 1);
    for (int n0 = blockIdx.x * 2; n0 < N; n0 += gridDim.x * 2) {
        int n = n0 + half;
        if (n < N) {
            const float* arow = agg + (size_t)n * FEAT;
            float acc = 0.0f;
#pragma unroll 16
            for (int k = 0; k < FEAT; ++k) acc = fmaf(arow[k], Wsf[k * FEAT + j], acc);
            float invd = 1.0f / fmaxf(deg[n], 1.0f);
            size_t idx = (size_t)n * FEAT + j;
            out[idx] = x[idx] + invd * acc;
        }
    }
}

extern "C" void kernel_launch(void* const* d_in, const int* in_sizes, int n_in,
                              void* d_out, int out_size, void* d_ws, size_t ws_size,
                              hipStream_t stream) {
    const float* x         = (const float*)d_in[0];
    const int*   ei        = (const int*)d_in[1];
    const float* edge_len  = (const float*)d_in[2];
    const float* W_mix     = (const float*)d_in[3];
    const float* log_scale = (const float*)d_in[4];
    const float* filter_w  = (const float*)d_in[5];
    const float* filter_b  = (const float*)d_in[6];
    float* out = (float*)d_out;

    const int N = in_sizes[0] / FEAT;
    const int E = in_sizes[1] / 2;
    const int* sender   = ei;
    const int* receiver = ei + E;
    const int nbuck = (N + BNODES - 1) >> BSHIFT;

    // ws layout: xbf [N*128 bf16], agg_bf [N*128 bf16], buf [E*8],
    // boff [(nbuck+1)*4], bcur [nbuck*4], deg [N*4]  -> ~37.8 MB
    size_t xbf_bytes  = (size_t)N * FEAT * 2;
    size_t aggb_bytes = (size_t)N * FEAT * 2;
    size_t buf_bytes  = (size_t)E * 8;
    size_t boff_bytes = (((size_t)(nbuck + 1) * 4) + 63) & ~(size_t)63;
    size_t bcur_bytes = (((size_t)nbuck * 4) + 63) & ~(size_t)63;
    size_t deg_bytes  = (((size_t)N * 4) + 63) & ~(size_t)63;
    size_t needed = xbf_bytes + aggb_bytes + buf_bytes + boff_bytes +
                    bcur_bytes + deg_bytes;

    if (ws_size >= needed && N <= 65536) {
        char* p = (char*)d_ws;
        uint2* xbf    = (uint2*)p;                        p += xbf_bytes;
        uint4* agg_bf = (uint4*)p;                        p += aggb_bytes;
        unsigned long long* buf = (unsigned long long*)p; p += buf_bytes;
        int* boff = (int*)p;                              p += boff_bytes;
        int* bcur = (int*)p;                              p += bcur_bytes;
        int* deg  = (int*)p;

        hipMemsetAsync(boff, 0, (size_t)(nbuck + 1) * 4, stream);

        int cblocks = (N * (FEAT / 4) + 255) / 256;
        convert_kernel<<<cblocks, 256, 0, stream>>>((const float4*)x, xbf,
                                                    N * (FEAT / 4));
        int chunkblocks = (E + EPB - 1) / EPB;
        count_kernel<<<chunkblocks, 256, 0, stream>>>(receiver, boff, E, nbuck);
        scan_kernel<<<1, 1024, 0, stream>>>(boff, bcur, nbuck);
        bucket_scatter_kernel<<<chunkblocks, 256, 0, stream>>>(
            sender, receiver, edge_len, log_scale, filter_w, filter_b,
            bcur, buf, E, nbuck);
        bucket_sort_aggregate_kernel<<<nbuck, 256, 0, stream>>>(
            (const uint4*)xbf, buf, boff, agg_bf, deg, N);
        int fblocks = (N + 63) / 64;
        finalize_kernel<<<fblocks, 256, 0, stream>>>(x, (const uint4*)agg_bf, deg,
                                                     W_mix, out, N);
    } else {
        float* agg = (float*)d_ws;
        float* degf = agg + (size_t)N * FEAT;
        hipMemsetAsync(agg, 0, ((size_t)N * FEAT + N) * sizeof(float), stream);
        int sblocks = (E * 32 + 255) / 256;
        scatter_fallback<<<sblocks, 256, 0, stream>>>(
            (const float4*)x, sender, receiver, edge_len,
            log_scale, filter_w, filter_b, agg, degf, E);
        finalize_fallback<<<512, 256, 0, stream>>>(x, agg, degf, W_mix, out, N);
    }
}